// Round 8
// baseline (4223.992 us; speedup 1.0000x reference)
//
#include <hip/hip_runtime.h>

#define DD 512
#define BB 64
#define VV 32000
#define TT 32
#define GRID 256
#define NTHR 512
#define NP 25
#define NTILE 500

typedef __attribute__((ext_vector_type(8))) short short8;
typedef __attribute__((ext_vector_type(4))) float f32x4;
typedef unsigned long long u64;
typedef unsigned int u32;

__device__ __forceinline__ float sigm(float x) { return 1.0f / (1.0f + __expf(-x)); }
__device__ __forceinline__ float ftanh(float x) {
  float e = __expf(2.0f * x);
  return 1.0f - 2.0f / (e + 1.0f);
}
__device__ __forceinline__ unsigned short f2bf(float f) {
  u32 u = __float_as_uint(f);
  u = (u + 0x7FFFu + ((u >> 16) & 1u)) >> 16;
  return (unsigned short)u;
}
__device__ __forceinline__ u64 pack4bf(float a, float b, float c, float d) {
  return (u64)f2bf(a) | ((u64)f2bf(b) << 16) | ((u64)f2bf(c) << 32) | ((u64)f2bf(d) << 48);
}
__device__ __forceinline__ u64 pack4bf4(float4 v) { return pack4bf(v.x, v.y, v.z, v.w); }

// ---- coherent (beyond-L2, sc0/sc1) accessors for mutable cross-block state ----
__device__ __forceinline__ void st_u32(u32* p, u32 v) {
  __hip_atomic_store(p, v, __ATOMIC_RELAXED, __HIP_MEMORY_SCOPE_AGENT);
}
__device__ __forceinline__ u32 ld_u32c(const u32* p) {
  return __hip_atomic_load(p, __ATOMIC_RELAXED, __HIP_MEMORY_SCOPE_AGENT);
}
__device__ __forceinline__ void st_u64c(u64* p, u64 v) {
  __hip_atomic_store(p, v, __ATOMIC_RELAXED, __HIP_MEMORY_SCOPE_AGENT);
}
__device__ __forceinline__ u64 ld_u64c(const u64* p) {
  return __hip_atomic_load(p, __ATOMIC_RELAXED, __HIP_MEMORY_SCOPE_AGENT);
}
__device__ __forceinline__ void st_f32(float* p, float v) { st_u32((u32*)p, __float_as_uint(v)); }
__device__ __forceinline__ float ld_f32(const float* p) { return __uint_as_float(ld_u32c((const u32*)p)); }
__device__ __forceinline__ float2 u64_to_f2(u64 v) {
  float2 r; r.x = __uint_as_float((u32)v); r.y = __uint_as_float((u32)(v >> 32)); return r;
}
__device__ __forceinline__ u64 f2_to_u64(float a, float b) {
  return (u64)__float_as_uint(a) | ((u64)__float_as_uint(b) << 32);
}

__device__ const float INVFACT[NP] = {
  1.0f, 1.0f, 0.5f, 1.6666667e-1f, 4.1666667e-2f, 8.3333333e-3f, 1.3888889e-3f,
  1.9841270e-4f, 2.4801587e-5f, 2.7557319e-6f, 2.7557319e-7f, 2.5052108e-8f,
  2.0876757e-9f, 1.6059044e-10f, 1.1470746e-11f, 7.6471637e-13f, 4.7794773e-14f,
  2.8114573e-15f, 1.5619207e-16f, 8.2206352e-18f, 4.1103176e-19f, 1.9572941e-20f,
  8.8967914e-22f, 3.8681702e-23f, 1.6117376e-24f
};

struct CellS {
  float4 xs4[16][129];
  float4 hs4[16][129];
  float gp[4][16][32];
  float ggv[16][32];
};
struct RecS {
  float fr[512], hs[512], wv[512], ctx[512], es[512];
  float mco[32], tco[32];
  float sred[8][32];
  float wred[16];
};
union SmemU {
  CellS cell;                       // 76.8 KB
  RecS rec;
  unsigned short bstage[32768];     // one 64-row vocab tile, fragment-blocked (64 KB)
};

// ---- flag-array grid barrier (relaxed atomics only, leader+broadcast) ----
__device__ __forceinline__ void gridsync(u32* flags, u32* go, unsigned& epoch) {
  epoch++;
  asm volatile("s_waitcnt vmcnt(0) lgkmcnt(0)" ::: "memory");
  __syncthreads();
  int tid = threadIdx.x, bid = blockIdx.x;
  if (bid == 0) {
    if (tid == 0) st_u32(flags, epoch);
    int ok;
    do {
      u32 f = (tid < GRID) ? ld_u32c(flags + (size_t)tid * 32) : epoch;
      ok = __syncthreads_and((int)(f >= epoch));
    } while (!ok);
    if (tid == 0) st_u32(go, epoch);
  } else {
    if (tid == 0) {
      st_u32(flags + (size_t)bid * 32, epoch);
      while (ld_u32c(go) < epoch) __builtin_amdgcn_s_sleep(8);
    }
    __syncthreads();
  }
}

__global__ void bar_init_k(u32* bar) {
  int i = blockIdx.x * 512 + threadIdx.x;
  if (i < 8704) bar[i] = 0u;
}

// ---- phase A: LSTM cell, fp32 VALU (unchanged, proven) ----
__device__ __forceinline__ void cell_phase(SmemU& SU, int bid,
    const float* __restrict__ Wih, const float* __restrict__ Whh,
    const float* __restrict__ bih, const float* __restrict__ bhh,
    const float* emb, const float* h_old, const float* c_old,
    float* h_new, float* c_new)
{
  CellS& S = SU.cell;
  int tid = threadIdx.x;
  int bg = bid >> 6, cg = bid & 63;
  int b0 = bg * 16, d0 = cg * 8;
  const u64* ep = (const u64*)emb;
  const u64* hp = (const u64*)h_old;
  for (int i = tid; i < 4096; i += NTHR) {
    int b = i >> 8, k2 = i & 255;
    float2 e2 = u64_to_f2(ld_u64c(ep + (size_t)(b0 + b) * 256 + k2));
    float2 h2 = u64_to_f2(ld_u64c(hp + (size_t)(b0 + b) * 256 + k2));
    ((float2*)&S.xs4[b][0])[k2] = e2;
    ((float2*)&S.hs4[b][0])[k2] = h2;
  }
  __syncthreads();
  {
    int ks = tid >> 7, sub = tid & 127, b = sub >> 3, dl = sub & 7;
    const float4* wi0 = (const float4*)(Wih + (size_t)(0 * 512 + d0 + dl) * 512) + ks * 32;
    const float4* wi1 = (const float4*)(Wih + (size_t)(1 * 512 + d0 + dl) * 512) + ks * 32;
    const float4* wi2 = (const float4*)(Wih + (size_t)(2 * 512 + d0 + dl) * 512) + ks * 32;
    const float4* wi3 = (const float4*)(Wih + (size_t)(3 * 512 + d0 + dl) * 512) + ks * 32;
    const float4* wh0 = (const float4*)(Whh + (size_t)(0 * 512 + d0 + dl) * 512) + ks * 32;
    const float4* wh1 = (const float4*)(Whh + (size_t)(1 * 512 + d0 + dl) * 512) + ks * 32;
    const float4* wh2 = (const float4*)(Whh + (size_t)(2 * 512 + d0 + dl) * 512) + ks * 32;
    const float4* wh3 = (const float4*)(Whh + (size_t)(3 * 512 + d0 + dl) * 512) + ks * 32;
    const float4* xr = &S.xs4[b][ks * 32];
    const float4* hr = &S.hs4[b][ks * 32];
    float a0 = 0.f, a1 = 0.f, a2 = 0.f, a3 = 0.f;
#pragma unroll 4
    for (int j = 0; j < 32; j++) {
      float4 xv = xr[j], hv = hr[j];
      float4 w;
      w = wi0[j]; a0 = fmaf(w.x, xv.x, a0); a0 = fmaf(w.y, xv.y, a0); a0 = fmaf(w.z, xv.z, a0); a0 = fmaf(w.w, xv.w, a0);
      w = wh0[j]; a0 = fmaf(w.x, hv.x, a0); a0 = fmaf(w.y, hv.y, a0); a0 = fmaf(w.z, hv.z, a0); a0 = fmaf(w.w, hv.w, a0);
      w = wi1[j]; a1 = fmaf(w.x, xv.x, a1); a1 = fmaf(w.y, xv.y, a1); a1 = fmaf(w.z, xv.z, a1); a1 = fmaf(w.w, xv.w, a1);
      w = wh1[j]; a1 = fmaf(w.x, hv.x, a1); a1 = fmaf(w.y, hv.y, a1); a1 = fmaf(w.z, hv.z, a1); a1 = fmaf(w.w, hv.w, a1);
      w = wi2[j]; a2 = fmaf(w.x, xv.x, a2); a2 = fmaf(w.y, xv.y, a2); a2 = fmaf(w.z, xv.z, a2); a2 = fmaf(w.w, xv.w, a2);
      w = wh2[j]; a2 = fmaf(w.x, hv.x, a2); a2 = fmaf(w.y, hv.y, a2); a2 = fmaf(w.z, hv.z, a2); a2 = fmaf(w.w, hv.w, a2);
      w = wi3[j]; a3 = fmaf(w.x, xv.x, a3); a3 = fmaf(w.y, xv.y, a3); a3 = fmaf(w.z, xv.z, a3); a3 = fmaf(w.w, xv.w, a3);
      w = wh3[j]; a3 = fmaf(w.x, hv.x, a3); a3 = fmaf(w.y, hv.y, a3); a3 = fmaf(w.z, hv.z, a3); a3 = fmaf(w.w, hv.w, a3);
    }
    S.gp[ks][b][dl * 4 + 0] = a0;
    S.gp[ks][b][dl * 4 + 1] = a1;
    S.gp[ks][b][dl * 4 + 2] = a2;
    S.gp[ks][b][dl * 4 + 3] = a3;
  }
  __syncthreads();
  {
    int b = tid >> 5, rg = tid & 31;
    float s = S.gp[0][b][rg] + S.gp[1][b][rg] + S.gp[2][b][rg] + S.gp[3][b][rg];
    int dl = rg >> 2, g = rg & 3;
    int r = g * 512 + d0 + dl;
    s += bih[r] + bhh[r];
    S.ggv[b][rg] = s;
  }
  __syncthreads();
  if (tid < 128) {
    int b = tid >> 3, dl = tid & 7;
    float gi = S.ggv[b][dl * 4 + 0];
    float gf = S.ggv[b][dl * 4 + 1];
    float gg = S.ggv[b][dl * 4 + 2];
    float go = S.ggv[b][dl * 4 + 3];
    size_t idx = (size_t)(b0 + b) * 512 + d0 + dl;
    float c2 = sigm(gf) * ld_f32(c_old + idx) + sigm(gi) * ftanh(gg);
    st_f32(c_new + idx, c2);
    st_f32(h_new + idx, sigm(go) * ftanh(c2));
  }
}

// ---- phase B (blocks 0..63): fp32 Taylor attention + zgemm + LN (unchanged) ----
__device__ __forceinline__ void rec_phase(SmemU& SU, int b,
    const float* __restrict__ feats, const float* h, const float* Mb,
    const float* __restrict__ Whc, const float* __restrict__ bhc,
    const float* __restrict__ gam, const float* __restrict__ bet,
    float* emb, u64* ebfOut)
{
  RecS& S = SU.rec;
  int tid = threadIdx.x;
  if (tid < 256) {
    float2 h2 = u64_to_f2(ld_u64c((const u64*)h + (size_t)b * 256 + tid));
    S.hs[2 * tid] = h2.x; S.hs[2 * tid + 1] = h2.y;
  } else {
    int t2 = tid - 256;
    float2 f2 = ((const float2*)feats)[(size_t)b * 256 + t2];
    S.fr[2 * t2] = f2.x; S.fr[2 * t2 + 1] = f2.y;
  }
  if (tid < NP) S.mco[tid] = ld_f32(Mb + b * NP + tid);
  __syncthreads();
  float hj = S.hs[tid];
  float fi = S.fr[tid];
  {
    float Z = S.mco[NP - 1];
#pragma unroll
    for (int k = NP - 2; k >= 0; k--) Z = fmaf(Z, hj, S.mco[k]);
    S.wv[tid] = fi / Z;
  }
  __syncthreads();
  {
    float part = S.wv[tid];
#pragma unroll
    for (int k = 0; k < NP; k++) {
      float v = part;
      v += __shfl_xor(v, 32); v += __shfl_xor(v, 16); v += __shfl_xor(v, 8);
      v += __shfl_xor(v, 4);  v += __shfl_xor(v, 2);  v += __shfl_xor(v, 1);
      if ((tid & 63) == 0) S.sred[tid >> 6][k] = v;
      part *= hj;
    }
  }
  __syncthreads();
  if (tid < NP) {
    float s = 0.f;
#pragma unroll
    for (int w = 0; w < 8; w++) s += S.sred[w][tid];
    S.tco[tid] = s * INVFACT[tid];
  }
  __syncthreads();
  {
    float C = S.tco[NP - 1];
#pragma unroll
    for (int k = NP - 2; k >= 0; k--) C = fmaf(C, fi, S.tco[k]);
    S.ctx[tid] = C;
  }
  __syncthreads();
  float z;
  {
    const float4* wrow = (const float4*)(Whc + (size_t)tid * 1024);
    const float4* hq = (const float4*)S.hs;
    const float4* cq = (const float4*)S.ctx;
    float acc = 0.f;
#pragma unroll 4
    for (int k4 = 0; k4 < 128; k4++) {
      float4 w = wrow[k4], x = hq[k4];
      acc = fmaf(w.x, x.x, acc); acc = fmaf(w.y, x.y, acc);
      acc = fmaf(w.z, x.z, acc); acc = fmaf(w.w, x.w, acc);
    }
#pragma unroll 4
    for (int k4 = 0; k4 < 128; k4++) {
      float4 w = wrow[128 + k4], x = cq[k4];
      acc = fmaf(w.x, x.x, acc); acc = fmaf(w.y, x.y, acc);
      acc = fmaf(w.z, x.z, acc); acc = fmaf(w.w, x.w, acc);
    }
    z = acc + bhc[tid];
  }
  {
    float v1 = z, v2 = z * z;
    v1 += __shfl_xor(v1, 32); v2 += __shfl_xor(v2, 32);
    v1 += __shfl_xor(v1, 16); v2 += __shfl_xor(v2, 16);
    v1 += __shfl_xor(v1, 8);  v2 += __shfl_xor(v2, 8);
    v1 += __shfl_xor(v1, 4);  v2 += __shfl_xor(v2, 4);
    v1 += __shfl_xor(v1, 2);  v2 += __shfl_xor(v2, 2);
    v1 += __shfl_xor(v1, 1);  v2 += __shfl_xor(v2, 1);
    if ((tid & 63) == 0) { S.wred[(tid >> 6) * 2] = v1; S.wred[(tid >> 6) * 2 + 1] = v2; }
  }
  __syncthreads();
  {
    float s1 = 0.f, s2 = 0.f;
#pragma unroll
    for (int w = 0; w < 8; w++) { s1 += S.wred[2 * w]; s2 += S.wred[2 * w + 1]; }
    float m = s1 * (1.0f / 512.0f);
    float var = s2 * (1.0f / 512.0f) - m * m;
    float rstd = rsqrtf(var + 1e-5f);
    float e = ftanh((z - m) * rstd * gam[tid] + bet[tid]);
    st_f32(emb + (size_t)b * 512 + tid, e);
    S.es[tid] = e;
  }
  __syncthreads();
  if (tid < 128) {
    u64 q = pack4bf(S.es[4 * tid], S.es[4 * tid + 1], S.es[4 * tid + 2], S.es[4 * tid + 3]);
    st_u64c(ebfOut + (size_t)b * 128 + tid, q);
  }
}

// ---- logits phase: deep-MLP tile streaming ----
// vocabT layout: tile q (64 vocab rows), fragment (s=0..63, r=0..63) of 16 B at
// byte offset q*65536 + (s*64+r)*16; fragment = vocab row q*64+r, k = s*8..s*8+7.
// Per block: all 8 waves cooperate on one tile. Wave w: mq=w&3 (A rows 16mq..+16),
// nh=w>>2 (B rows/cols 32nh..+32). A held in 64 VGPRs/lane (loaded once/phase).
__device__ __forceinline__ void logits_phase(unsigned short* bstage,
    const u64* ebf, const unsigned short* __restrict__ vocabT,
    const float* __restrict__ vbias, float* __restrict__ out,
    int q0, int q1, int q2)
{
  int tid = threadIdx.x;
  int w = tid >> 6, l = tid & 63, lm = l & 15, kb = l >> 4;
  int mq = w & 3, nh = w >> 2;
  int m = mq * 16 + lm;
  // A fragments (emb row m), coherent: areg[kt] covers k = kt*32 + kb*8 .. +8
  short8 areg[16];
  {
    const u64* ap = ebf + (size_t)m * 128 + kb * 2;
#pragma unroll
    for (int kt = 0; kt < 16; kt++) {
      union { short8 v; u64 qq[2]; } u;
      u.qq[0] = ld_u64c(ap + kt * 8);
      u.qq[1] = ld_u64c(ap + kt * 8 + 1);
      areg[kt] = u.v;
    }
  }
  int qs0 = q0, qs1 = q1, qs2 = q2;
#pragma unroll
  for (int i = 0; i < 3; i++) {
    int q = (i == 0) ? qs0 : (i == 1) ? qs1 : qs2;
    if (q < 0 || q >= NTILE) continue;   // uniform per block -> barrier-safe skip
    // --- stage tile q: 512 thr x 8 fragments; 16 coherent u64 loads in flight ---
    const u64* src = (const u64*)vocabT + (size_t)q * 8192;
    u64 t0, t1, t2, t3, t4, t5, t6, t7, t8, t9, ta, tb, tc, td, te, tf;
    int f0 = (w * 8 + 0) * 64 + l, f1 = (w * 8 + 1) * 64 + l;
    int f2 = (w * 8 + 2) * 64 + l, f3 = (w * 8 + 3) * 64 + l;
    int f4 = (w * 8 + 4) * 64 + l, f5 = (w * 8 + 5) * 64 + l;
    int f6 = (w * 8 + 6) * 64 + l, f7 = (w * 8 + 7) * 64 + l;
    t0 = ld_u64c(src + f0 * 2);     t1 = ld_u64c(src + f0 * 2 + 1);
    t2 = ld_u64c(src + f1 * 2);     t3 = ld_u64c(src + f1 * 2 + 1);
    t4 = ld_u64c(src + f2 * 2);     t5 = ld_u64c(src + f2 * 2 + 1);
    t6 = ld_u64c(src + f3 * 2);     t7 = ld_u64c(src + f3 * 2 + 1);
    t8 = ld_u64c(src + f4 * 2);     t9 = ld_u64c(src + f4 * 2 + 1);
    ta = ld_u64c(src + f5 * 2);     tb = ld_u64c(src + f5 * 2 + 1);
    tc = ld_u64c(src + f6 * 2);     td = ld_u64c(src + f6 * 2 + 1);
    te = ld_u64c(src + f7 * 2);     tf = ld_u64c(src + f7 * 2 + 1);
    {
      union { short8 v; u64 qq[2]; } u;
      u.qq[0] = t0; u.qq[1] = t1; *(short8*)(bstage + f0 * 8) = u.v;
      u.qq[0] = t2; u.qq[1] = t3; *(short8*)(bstage + f1 * 8) = u.v;
      u.qq[0] = t4; u.qq[1] = t5; *(short8*)(bstage + f2 * 8) = u.v;
      u.qq[0] = t6; u.qq[1] = t7; *(short8*)(bstage + f3 * 8) = u.v;
      u.qq[0] = t8; u.qq[1] = t9; *(short8*)(bstage + f4 * 8) = u.v;
      u.qq[0] = ta; u.qq[1] = tb; *(short8*)(bstage + f5 * 8) = u.v;
      u.qq[0] = tc; u.qq[1] = td; *(short8*)(bstage + f6 * 8) = u.v;
      u.qq[0] = te; u.qq[1] = tf; *(short8*)(bstage + f7 * 8) = u.v;
    }
    asm volatile("s_waitcnt vmcnt(0) lgkmcnt(0)" ::: "memory");
    __syncthreads();
    // --- compute 64x64 tile ---
    int n0 = q * 64;
    f32x4 acc0 = {}, acc1 = {};
    int nt0 = nh * 2, nt1 = nh * 2 + 1;
#pragma unroll
    for (int kt = 0; kt < 16; kt++) {
      short8 a = areg[kt];
      int sbase = (kt * 4 + kb) * 64;
      short8 bv0 = *(const short8*)(bstage + (sbase + nt0 * 16 + lm) * 8);
      short8 bv1 = *(const short8*)(bstage + (sbase + nt1 * 16 + lm) * 8);
      acc0 = __builtin_amdgcn_mfma_f32_16x16x32_bf16(a, bv0, acc0, 0, 0, 0);
      acc1 = __builtin_amdgcn_mfma_f32_16x16x32_bf16(a, bv1, acc1, 0, 0, 0);
    }
    int rbase = mq * 16 + kb * 4;   // C/D: col = lane&15, row = (lane>>4)*4 + reg
    {
      int v = n0 + nt0 * 16 + lm;
      float bias = vbias[v];
#pragma unroll
      for (int r = 0; r < 4; r++)
        __builtin_nontemporal_store(acc0[r] + bias, &out[(size_t)(rbase + r) * 32000 + v]);
    }
    {
      int v = n0 + nt1 * 16 + lm;
      float bias = vbias[v];
#pragma unroll
      for (int r = 0; r < 4; r++)
        __builtin_nontemporal_store(acc1[r] + bias, &out[(size_t)(rbase + r) * 32000 + v]);
    }
    __syncthreads();   // before next stage overwrites bstage
  }
}

// ---- persistent kernel ----
__global__ __launch_bounds__(NTHR, 1) void persist_k(
    const float* __restrict__ feats, const float* __restrict__ Wih, const float* __restrict__ Whh,
    const float* __restrict__ bih, const float* __restrict__ bhh,
    const float* __restrict__ Whc, const float* __restrict__ bhc,
    const float* __restrict__ gam, const float* __restrict__ bet,
    const float* __restrict__ vemb, const float* __restrict__ vbias,
    unsigned short* vocabT, float* hA, float* hB, float* cA, float* cB,
    float* emb, u64* ebf0, u64* ebf1, float* Mb, float* out, u32* bar)
{
  __shared__ SmemU SU;
  const int bid = blockIdx.x, tid = threadIdx.x;
  unsigned epoch = 0;
  u32* flags = bar;
  u32* go = bar + GRID * 32 + 16;

  // prologue: vocab fp32 -> bf16 tile-fragment-blocked layout
  {
    const float4* vp = (const float4*)vemb;
    u64* vt = (u64*)vocabT;
    const int TFRAG = NTILE * 64 * 64;   // 2,048,000 fragments of 16 B
    for (int i = bid * NTHR + tid; i < TFRAG; i += GRID * NTHR) {
      int q = i >> 12, s = (i >> 6) & 63, r = i & 63;
      int row = q * 64 + r;
      float4 a = vp[(size_t)row * 128 + s * 2];
      float4 b = vp[(size_t)row * 128 + s * 2 + 1];
      st_u64c(vt + (size_t)i * 2, pack4bf4(a));
      st_u64c(vt + (size_t)i * 2 + 1, pack4bf4(b));
    }
  }
  {
    const float4* fp4 = (const float4*)feats;
    const float4* vp0 = (const float4*)vemb;
    for (int i = bid * NTHR + tid; i < BB * DD / 4; i += GRID * NTHR) {
      float4 f = fp4[i];
      st_u64c((u64*)cA + 2 * (size_t)i,     f2_to_u64(f.x, f.y));
      st_u64c((u64*)cA + 2 * (size_t)i + 1, f2_to_u64(f.z, f.w));
      st_u64c((u64*)hA + 2 * (size_t)i,     f2_to_u64(f.x, f.y));
      st_u64c((u64*)hA + 2 * (size_t)i + 1, f2_to_u64(f.z, f.w));
      float4 e = vp0[i & 127];
      st_u64c((u64*)emb + 2 * (size_t)i,     f2_to_u64(e.x, e.y));
      st_u64c((u64*)emb + 2 * (size_t)i + 1, f2_to_u64(e.z, e.w));
    }
  }
  if (bid < 64) {  // M_k[b] = (sum_i f_i^k) / k!
    float f = feats[(size_t)bid * 512 + tid];
    float part = 1.f;
#pragma unroll
    for (int k = 0; k < NP; k++) {
      float v = part;
      v += __shfl_xor(v, 32); v += __shfl_xor(v, 16); v += __shfl_xor(v, 8);
      v += __shfl_xor(v, 4);  v += __shfl_xor(v, 2);  v += __shfl_xor(v, 1);
      if ((tid & 63) == 0) SU.rec.sred[tid >> 6][k] = v;
      part *= f;
    }
    __syncthreads();
    if (tid < NP) {
      float s = 0.f;
#pragma unroll
      for (int w = 0; w < 8; w++) s += SU.rec.sred[w][tid];
      st_f32(Mb + bid * NP + tid, s * INVFACT[tid]);
    }
  }
  gridsync(flags, go, epoch);

  for (int t = 0; t < TT; t++) {
    float* ho = (t & 1) ? hB : hA; float* hn = (t & 1) ? hA : hB;
    const float* co = (t & 1) ? cB : cA; float* cn = (t & 1) ? cA : cB;
    u64* ebfOut = (t & 1) ? ebf0 : ebf1;
    const u64* ebfPrev = (t & 1) ? ebf1 : ebf0;

    // A: cell(t) on all 256 blocks
    cell_phase(SU, bid, Wih, Whh, bih, bhh, emb, ho, co, hn, cn);
    gridsync(flags, go, epoch);

    // B: rec(t) on 0..63 | logits(t-1) on 64..255
    if (bid < 64) {
      rec_phase(SU, bid, feats, hn, Mb, Whc, bhc, gam, bet, emb, ebfOut);
    } else if (t >= 1) {
      float* out_prev = out + (size_t)(t - 1) * BB * VV;
      int idx = bid - 64;
      int q0, q1, q2;
      if (idx < 116) { q0 = idx * 3; q1 = q0 + 1; q2 = q0 + 2; }
      else           { q0 = 348 + (idx - 116) * 2; q1 = q0 + 1; q2 = -1; }
      logits_phase(SU.bstage, ebfPrev, vocabT, vbias, out_prev, q0, q1, q2);
    }
    gridsync(flags, go, epoch);
  }

  // drain: logits(31) on all 256 blocks, 2 tiles each (t=31 wrote ebf0)
  {
    float* o31 = out + (size_t)(TT - 1) * BB * VV;
    int q0 = bid * 2, q1 = bid * 2 + 1;
    logits_phase(SU.bstage, ebf0, vocabT, vbias, o31, q0, q1, -1);
  }
}

extern "C" void kernel_launch(void* const* d_in, const int* in_sizes, int n_in,
                              void* d_out, int out_size, void* d_ws, size_t ws_size,
                              hipStream_t stream) {
  const float* feats = (const float*)d_in[0];
  const float* Wih   = (const float*)d_in[1];
  const float* Whh   = (const float*)d_in[2];
  const float* bih   = (const float*)d_in[3];
  const float* bhh   = (const float*)d_in[4];
  const float* Whc   = (const float*)d_in[5];
  const float* bhc   = (const float*)d_in[6];
  const float* gam   = (const float*)d_in[7];
  const float* bet   = (const float*)d_in[8];
  const float* vemb  = (const float*)d_in[9];
  const float* vbias = (const float*)d_in[10];
  float* out = (float*)d_out;

  char* p = (char*)d_ws;
  unsigned short* vocabT = (unsigned short*)p; p += (size_t)VV * DD * 2;  // 32.77MB
  float* hA  = (float*)p; p += (size_t)BB * DD * 4;
  float* hB  = (float*)p; p += (size_t)BB * DD * 4;
  float* cA  = (float*)p; p += (size_t)BB * DD * 4;
  float* cB  = (float*)p; p += (size_t)BB * DD * 4;
  float* emb = (float*)p; p += (size_t)BB * DD * 4;
  u64* ebf0  = (u64*)p;   p += (size_t)BB * DD * 2;
  u64* ebf1  = (u64*)p;   p += (size_t)BB * DD * 2;
  float* Mb  = (float*)p; p += 64 * NP * 4 + 112;
  u32* bar   = (u32*)p;   p += 8704 * 4;

  bar_init_k<<<17, 512, 0, stream>>>(bar);
  persist_k<<<GRID, NTHR, 0, stream>>>(feats, Wih, Whh, bih, bhh, Whc, bhc, gam, bet,
                                       vemb, vbias, vocabT, hA, hB, cA, cB, emb,
                                       ebf0, ebf1, Mb, out, bar);
}

// Round 9
// 3281.809 us; speedup vs baseline: 1.2871x; 1.2871x over previous
//
#include <hip/hip_runtime.h>

#define DD 512
#define BB 64
#define VV 32000
#define TT 32
#define NP 25
#define NTILE 500

typedef __attribute__((ext_vector_type(8))) short short8;
typedef __attribute__((ext_vector_type(4))) float f32x4;
typedef __attribute__((ext_vector_type(4))) unsigned short ushort4v;
typedef unsigned long long u64;
typedef unsigned int u32;

__device__ __forceinline__ float sigm(float x) { return 1.0f / (1.0f + __expf(-x)); }
__device__ __forceinline__ float ftanh(float x) {
  float e = __expf(2.0f * x);
  return 1.0f - 2.0f / (e + 1.0f);
}
__device__ __forceinline__ unsigned short f2bf(float f) {
  u32 u = __float_as_uint(f);
  u = (u + 0x7FFFu + ((u >> 16) & 1u)) >> 16;
  return (unsigned short)u;
}
__device__ __forceinline__ u64 pack4bf(float a, float b, float c, float d) {
  return (u64)f2bf(a) | ((u64)f2bf(b) << 16) | ((u64)f2bf(c) << 32) | ((u64)f2bf(d) << 48);
}

__device__ const float INVFACT[NP] = {
  1.0f, 1.0f, 0.5f, 1.6666667e-1f, 4.1666667e-2f, 8.3333333e-3f, 1.3888889e-3f,
  1.9841270e-4f, 2.4801587e-5f, 2.7557319e-6f, 2.7557319e-7f, 2.5052108e-8f,
  2.0876757e-9f, 1.6059044e-10f, 1.1470746e-11f, 7.6471637e-13f, 4.7794773e-14f,
  2.8114573e-15f, 1.5619207e-16f, 8.2206352e-18f, 4.1103176e-19f, 1.9572941e-20f,
  8.8967914e-22f, 3.8681702e-23f, 1.6117376e-24f
};

// ---- prep: vocab fp32 -> bf16 (once) ----
__global__ __launch_bounds__(256) void prep_vocab_k(const float* __restrict__ v,
                                                    unsigned short* __restrict__ o) {
  size_t i = (size_t)blockIdx.x * 256 + threadIdx.x;  // 4,096,000 float4s exactly
  float4 x = ((const float4*)v)[i];
  ushort4v y;
  y.x = f2bf(x.x); y.y = f2bf(x.y); y.z = f2bf(x.z); y.w = f2bf(x.w);
  ((ushort4v*)o)[i] = y;
}

// ---- init: h=c=feats, emb=vocab[0]; f-moments Mb[b][k] ----
__global__ __launch_bounds__(512) void init_k(const float* __restrict__ feats,
    const float* __restrict__ vemb, float* __restrict__ h, float* __restrict__ c,
    float* __restrict__ emb, float* __restrict__ Mb)
{
  __shared__ float sred[8][32];
  int b = blockIdx.x, tid = threadIdx.x;
  float f = feats[(size_t)b * 512 + tid];
  h[(size_t)b * 512 + tid] = f;
  c[(size_t)b * 512 + tid] = f;
  emb[(size_t)b * 512 + tid] = vemb[tid];
  float part = 1.f;
#pragma unroll
  for (int k = 0; k < NP; k++) {
    float v = part;
    v += __shfl_xor(v, 32); v += __shfl_xor(v, 16); v += __shfl_xor(v, 8);
    v += __shfl_xor(v, 4);  v += __shfl_xor(v, 2);  v += __shfl_xor(v, 1);
    if ((tid & 63) == 0) sred[tid >> 6][k] = v;
    part *= f;
  }
  __syncthreads();
  if (tid < NP) {
    float s = 0.f;
#pragma unroll
    for (int w = 0; w < 8; w++) s += sred[w][tid];
    Mb[b * NP + tid] = s * INVFACT[tid];
  }
}

// ---- K1: LSTM cell, fp32 VALU (R5 structure, plain loads) ----
// grid 256 = 4 bgroups(16 b) x 64 colgroups(8 d), 512 thr = 4 K-splits x (16b x 8d)
__global__ __launch_bounds__(512) void cell_k(
    const float* __restrict__ Wih, const float* __restrict__ Whh,
    const float* __restrict__ bih, const float* __restrict__ bhh,
    const float* __restrict__ emb, const float* __restrict__ h_old,
    const float* __restrict__ c_old, float* __restrict__ h_new, float* __restrict__ c_new)
{
  __shared__ float4 xs4[16][129];
  __shared__ float4 hs4[16][129];
  __shared__ float gp[4][16][32];
  __shared__ float ggv[16][32];
  int tid = threadIdx.x, bid = blockIdx.x;
  int bg = bid >> 6, cg = bid & 63;
  int b0 = bg * 16, d0 = cg * 8;
  const float4* ep = (const float4*)emb;
  const float4* hp = (const float4*)h_old;
  for (int i = tid; i < 2048; i += 512) {
    int b = i >> 7, k4 = i & 127;
    xs4[b][k4] = ep[(size_t)(b0 + b) * 128 + k4];
    hs4[b][k4] = hp[(size_t)(b0 + b) * 128 + k4];
  }
  __syncthreads();
  {
    int ks = tid >> 7, sub = tid & 127, b = sub >> 3, dl = sub & 7;
    const float4* wi0 = (const float4*)(Wih + (size_t)(0 * 512 + d0 + dl) * 512) + ks * 32;
    const float4* wi1 = (const float4*)(Wih + (size_t)(1 * 512 + d0 + dl) * 512) + ks * 32;
    const float4* wi2 = (const float4*)(Wih + (size_t)(2 * 512 + d0 + dl) * 512) + ks * 32;
    const float4* wi3 = (const float4*)(Wih + (size_t)(3 * 512 + d0 + dl) * 512) + ks * 32;
    const float4* wh0 = (const float4*)(Whh + (size_t)(0 * 512 + d0 + dl) * 512) + ks * 32;
    const float4* wh1 = (const float4*)(Whh + (size_t)(1 * 512 + d0 + dl) * 512) + ks * 32;
    const float4* wh2 = (const float4*)(Whh + (size_t)(2 * 512 + d0 + dl) * 512) + ks * 32;
    const float4* wh3 = (const float4*)(Whh + (size_t)(3 * 512 + d0 + dl) * 512) + ks * 32;
    const float4* xr = &xs4[b][ks * 32];
    const float4* hr = &hs4[b][ks * 32];
    float a0 = 0.f, a1 = 0.f, a2 = 0.f, a3 = 0.f;
#pragma unroll 4
    for (int j = 0; j < 32; j++) {
      float4 xv = xr[j], hv = hr[j];
      float4 w;
      w = wi0[j]; a0 = fmaf(w.x, xv.x, a0); a0 = fmaf(w.y, xv.y, a0); a0 = fmaf(w.z, xv.z, a0); a0 = fmaf(w.w, xv.w, a0);
      w = wh0[j]; a0 = fmaf(w.x, hv.x, a0); a0 = fmaf(w.y, hv.y, a0); a0 = fmaf(w.z, hv.z, a0); a0 = fmaf(w.w, hv.w, a0);
      w = wi1[j]; a1 = fmaf(w.x, xv.x, a1); a1 = fmaf(w.y, xv.y, a1); a1 = fmaf(w.z, xv.z, a1); a1 = fmaf(w.w, xv.w, a1);
      w = wh1[j]; a1 = fmaf(w.x, hv.x, a1); a1 = fmaf(w.y, hv.y, a1); a1 = fmaf(w.z, hv.z, a1); a1 = fmaf(w.w, hv.w, a1);
      w = wi2[j]; a2 = fmaf(w.x, xv.x, a2); a2 = fmaf(w.y, xv.y, a2); a2 = fmaf(w.z, xv.z, a2); a2 = fmaf(w.w, xv.w, a2);
      w = wh2[j]; a2 = fmaf(w.x, hv.x, a2); a2 = fmaf(w.y, hv.y, a2); a2 = fmaf(w.z, hv.z, a2); a2 = fmaf(w.w, hv.w, a2);
      w = wi3[j]; a3 = fmaf(w.x, xv.x, a3); a3 = fmaf(w.y, xv.y, a3); a3 = fmaf(w.z, xv.z, a3); a3 = fmaf(w.w, xv.w, a3);
      w = wh3[j]; a3 = fmaf(w.x, hv.x, a3); a3 = fmaf(w.y, hv.y, a3); a3 = fmaf(w.z, hv.z, a3); a3 = fmaf(w.w, hv.w, a3);
    }
    gp[ks][b][dl * 4 + 0] = a0;
    gp[ks][b][dl * 4 + 1] = a1;
    gp[ks][b][dl * 4 + 2] = a2;
    gp[ks][b][dl * 4 + 3] = a3;
  }
  __syncthreads();
  {
    int b = tid >> 5, rg = tid & 31;
    float s = gp[0][b][rg] + gp[1][b][rg] + gp[2][b][rg] + gp[3][b][rg];
    int dl = rg >> 2, g = rg & 3;
    int r = g * 512 + d0 + dl;
    s += bih[r] + bhh[r];
    ggv[b][rg] = s;
  }
  __syncthreads();
  if (tid < 128) {
    int b = tid >> 3, dl = tid & 7;
    float gi = ggv[b][dl * 4 + 0];
    float gf = ggv[b][dl * 4 + 1];
    float gg = ggv[b][dl * 4 + 2];
    float go = ggv[b][dl * 4 + 3];
    size_t idx = (size_t)(b0 + b) * 512 + d0 + dl;
    float c2 = sigm(gf) * c_old[idx] + sigm(gi) * ftanh(gg);
    c_new[idx] = c2;
    h_new[idx] = sigm(go) * ftanh(c2);
  }
}

// ---- K2: blocks 0..63 rec(t) | blocks 64..313 logits(t-1), 512 thr ----
__global__ __launch_bounds__(512) void step_k(
    const float* __restrict__ feats, const float* __restrict__ h,
    const float* __restrict__ Mb, const float* __restrict__ Whc,
    const float* __restrict__ bhc, const float* __restrict__ gam,
    const float* __restrict__ bet, float* __restrict__ emb, u64* __restrict__ ebfOut,
    const unsigned short* __restrict__ ebfPrev, const unsigned short* __restrict__ vocab_bf,
    const float* __restrict__ vbias, float* __restrict__ outPrev,
    int do_rec, int do_logits)
{
  int bid = blockIdx.x, tid = threadIdx.x;
  if (bid < 64) {
    if (!do_rec) return;
    __shared__ float fr[512], hs[512], wv[512], ctx[512], es[512];
    __shared__ float mco[32], tco[32], sred[8][32], wred[16];
    int b = bid;
    if (tid < 256) {
      float2 h2 = ((const float2*)h)[(size_t)b * 256 + tid];
      hs[2 * tid] = h2.x; hs[2 * tid + 1] = h2.y;
    } else {
      int t2 = tid - 256;
      float2 f2 = ((const float2*)feats)[(size_t)b * 256 + t2];
      fr[2 * t2] = f2.x; fr[2 * t2 + 1] = f2.y;
    }
    if (tid < NP) mco[tid] = Mb[b * NP + tid];
    __syncthreads();
    float hj = hs[tid], fi = fr[tid];
    // Z_j via Horner in h_j; wv_j = f_j / Z_j
    {
      float Z = mco[NP - 1];
#pragma unroll
      for (int k = NP - 2; k >= 0; k--) Z = fmaf(Z, hj, mco[k]);
      wv[tid] = fi / Z;
    }
    __syncthreads();
    // h-moments S_k = sum_j h_j^k wv_j
    {
      float part = wv[tid];
#pragma unroll
      for (int k = 0; k < NP; k++) {
        float v = part;
        v += __shfl_xor(v, 32); v += __shfl_xor(v, 16); v += __shfl_xor(v, 8);
        v += __shfl_xor(v, 4);  v += __shfl_xor(v, 2);  v += __shfl_xor(v, 1);
        if ((tid & 63) == 0) sred[tid >> 6][k] = v;
        part *= hj;
      }
    }
    __syncthreads();
    if (tid < NP) {
      float s = 0.f;
#pragma unroll
      for (int w = 0; w < 8; w++) s += sred[w][tid];
      tco[tid] = s * INVFACT[tid];
    }
    __syncthreads();
    // ctx_i via Horner in f_i
    {
      float C = tco[NP - 1];
#pragma unroll
      for (int k = NP - 2; k >= 0; k--) C = fmaf(C, fi, tco[k]);
      ctx[tid] = C;
    }
    __syncthreads();
    // zgemm: 8 lanes per row (coalesced 128B segments), 8-way shfl reduce
    {
      int s = tid & 7;
      const float4* hq = (const float4*)hs;
      const float4* cq = (const float4*)ctx;
#pragma unroll
      for (int j = 0; j < 8; j++) {
        int r = (tid >> 3) + j * 64;
        const float4* wrow = (const float4*)(Whc + (size_t)r * 1024);
        float acc = 0.f;
#pragma unroll 4
        for (int i = 0; i < 16; i++) {
          int k4 = i * 8 + s;
          float4 w = wrow[k4], x = hq[k4];
          acc = fmaf(w.x, x.x, acc); acc = fmaf(w.y, x.y, acc);
          acc = fmaf(w.z, x.z, acc); acc = fmaf(w.w, x.w, acc);
        }
#pragma unroll 4
        for (int i = 0; i < 16; i++) {
          int k4 = i * 8 + s;
          float4 w = wrow[128 + k4], x = cq[k4];
          acc = fmaf(w.x, x.x, acc); acc = fmaf(w.y, x.y, acc);
          acc = fmaf(w.z, x.z, acc); acc = fmaf(w.w, x.w, acc);
        }
        acc += __shfl_xor(acc, 1);
        acc += __shfl_xor(acc, 2);
        acc += __shfl_xor(acc, 4);
        if (s == 0) es[r] = acc + bhc[r];
      }
    }
    __syncthreads();
    float z = es[tid];
    // LayerNorm reduce
    {
      float v1 = z, v2 = z * z;
      v1 += __shfl_xor(v1, 32); v2 += __shfl_xor(v2, 32);
      v1 += __shfl_xor(v1, 16); v2 += __shfl_xor(v2, 16);
      v1 += __shfl_xor(v1, 8);  v2 += __shfl_xor(v2, 8);
      v1 += __shfl_xor(v1, 4);  v2 += __shfl_xor(v2, 4);
      v1 += __shfl_xor(v1, 2);  v2 += __shfl_xor(v2, 2);
      v1 += __shfl_xor(v1, 1);  v2 += __shfl_xor(v2, 1);
      if ((tid & 63) == 0) { wred[(tid >> 6) * 2] = v1; wred[(tid >> 6) * 2 + 1] = v2; }
    }
    __syncthreads();
    {
      float s1 = 0.f, s2 = 0.f;
#pragma unroll
      for (int w = 0; w < 8; w++) { s1 += wred[2 * w]; s2 += wred[2 * w + 1]; }
      float m = s1 * (1.0f / 512.0f);
      float var = s2 * (1.0f / 512.0f) - m * m;
      float rstd = rsqrtf(var + 1e-5f);
      float e = ftanh((z - m) * rstd * gam[tid] + bet[tid]);
      emb[(size_t)b * 512 + tid] = e;
      es[tid] = e;
    }
    __syncthreads();
    if (tid < 128) {
      u64 q = pack4bf(es[4 * tid], es[4 * tid + 1], es[4 * tid + 2], es[4 * tid + 3]);
      ebfOut[(size_t)b * 128 + tid] = q;
    }
  } else {
    if (!do_logits) return;
    // two 256-thread units per block; unit = vocab tile q
    int q = (bid - 64) * 2 + (tid >> 8);
    if (q >= NTILE) return;
    int n0 = q * 64;
    int ut = tid & 255;
    int w = ut >> 6, l = ut & 63;
    int lm = l & 15, kb = l >> 4;
    int m = w * 16 + lm;
    f32x4 acc[4] = {};
    const short8* ap = (const short8*)(ebfPrev + (size_t)m * 512);
    const short8* bp0 = (const short8*)(vocab_bf + (size_t)(n0 +  0 + lm) * 512) + kb;
    const short8* bp1 = (const short8*)(vocab_bf + (size_t)(n0 + 16 + lm) * 512) + kb;
    const short8* bp2 = (const short8*)(vocab_bf + (size_t)(n0 + 32 + lm) * 512) + kb;
    const short8* bp3 = (const short8*)(vocab_bf + (size_t)(n0 + 48 + lm) * 512) + kb;
    short8 bA[4], bB[4];
    bA[0] = bp0[0]; bA[1] = bp1[0]; bA[2] = bp2[0]; bA[3] = bp3[0];
    bB[0] = bp0[4]; bB[1] = bp1[4]; bB[2] = bp2[4]; bB[3] = bp3[4];
#pragma unroll
    for (int kt = 0; kt < 16; kt++) {
      short8 a = ap[kt * 4 + kb];
      short8* bc = (kt & 1) ? bB : bA;   // holds kt's fragments
      acc[0] = __builtin_amdgcn_mfma_f32_16x16x32_bf16(a, bc[0], acc[0], 0, 0, 0);
      acc[1] = __builtin_amdgcn_mfma_f32_16x16x32_bf16(a, bc[1], acc[1], 0, 0, 0);
      acc[2] = __builtin_amdgcn_mfma_f32_16x16x32_bf16(a, bc[2], acc[2], 0, 0, 0);
      acc[3] = __builtin_amdgcn_mfma_f32_16x16x32_bf16(a, bc[3], acc[3], 0, 0, 0);
      if (kt < 14) {                     // refill just-consumed buffer with kt+2
        int o = (kt + 2) * 4;
        bc[0] = bp0[o]; bc[1] = bp1[o]; bc[2] = bp2[o]; bc[3] = bp3[o];
      }
    }
    int rbase = w * 16 + kb * 4;  // C/D: col = lane&15, row = (lane>>4)*4 + reg
#pragma unroll
    for (int nt = 0; nt < 4; nt++) {
      int v = n0 + nt * 16 + lm;
      float bias = vbias[v];
#pragma unroll
      for (int r = 0; r < 4; r++) {
        __builtin_nontemporal_store(acc[nt][r] + bias,
                                    &outPrev[(size_t)(rbase + r) * 32000 + v]);
      }
    }
  }
}

extern "C" void kernel_launch(void* const* d_in, const int* in_sizes, int n_in,
                              void* d_out, int out_size, void* d_ws, size_t ws_size,
                              hipStream_t stream) {
  const float* feats = (const float*)d_in[0];
  const float* Wih   = (const float*)d_in[1];
  const float* Whh   = (const float*)d_in[2];
  const float* bih   = (const float*)d_in[3];
  const float* bhh   = (const float*)d_in[4];
  const float* Whc   = (const float*)d_in[5];
  const float* bhc   = (const float*)d_in[6];
  const float* gam   = (const float*)d_in[7];
  const float* bet   = (const float*)d_in[8];
  const float* vemb  = (const float*)d_in[9];
  const float* vbias = (const float*)d_in[10];
  float* out = (float*)d_out;

  char* p = (char*)d_ws;
  unsigned short* vocab_bf = (unsigned short*)p; p += (size_t)VV * DD * 2;  // 32.77MB
  float* hA  = (float*)p; p += (size_t)BB * DD * 4;
  float* hB  = (float*)p; p += (size_t)BB * DD * 4;
  float* cA  = (float*)p; p += (size_t)BB * DD * 4;
  float* cB  = (float*)p; p += (size_t)BB * DD * 4;
  float* emb = (float*)p; p += (size_t)BB * DD * 4;
  u64* ebfA  = (u64*)p;   p += (size_t)BB * DD * 2;
  u64* ebfB  = (u64*)p;   p += (size_t)BB * DD * 2;
  float* Mb  = (float*)p; p += 64 * NP * 4;

  prep_vocab_k<<<16000, 256, 0, stream>>>(vemb, vocab_bf);
  init_k<<<64, 512, 0, stream>>>(feats, vemb, hA, cA, emb, Mb);

  for (int t = 0; t < TT; t++) {
    float* ho = (t & 1) ? hB : hA; float* hn = (t & 1) ? hA : hB;
    float* co = (t & 1) ? cB : cA; float* cn = (t & 1) ? cA : cB;
    u64* ebfCur = (t & 1) ? ebfB : ebfA;
    const unsigned short* ebfPrev = (const unsigned short*)((t & 1) ? ebfA : ebfB);
    float* outPrev = (t >= 1) ? out + (size_t)(t - 1) * BB * VV : out;

    cell_k<<<256, 512, 0, stream>>>(Wih, Whh, bih, bhh, emb, ho, co, hn, cn);
    step_k<<<314, 512, 0, stream>>>(feats, hn, Mb, Whc, bhc, gam, bet, emb, ebfCur,
                                    ebfPrev, vocab_bf, vbias, outPrev,
                                    1, (t >= 1) ? 1 : 0);
  }
  // drain: logits(31) — rec off; t=31 odd wrote ebfB
  step_k<<<314, 512, 0, stream>>>(feats, hA, Mb, Whc, bhc, gam, bet, emb, ebfA,
                                  (const unsigned short*)ebfB, vocab_bf, vbias,
                                  out + (size_t)(TT - 1) * BB * VV, 0, 1);
}